// Round 8
// baseline (167.148 us; speedup 1.0000x reference)
//
#include <hip/hip_runtime.h>

// LSA single-kernel, zero-workspace (R8). Decisive test of "multi-kernel +
// round-trip overhead" vs "harness floor" hypotheses. All arithmetic chains
// verbatim R5 (verified, absmax 0.125): fmap f32 -> f2bf -> stencil -> f2bf ->
// MFMA bf16 GEMM w/ f2bf(Wv) -> fp32 residual. New code is only data movement:
// chunked in-LDS transpose (fmap -> hs) and register-built Wv fragments.
// B=4, C=128, H=64, W=128, L=25.

namespace {
constexpr int Bn = 4, Cn = 128, Hn = 64, Wn = 128, Ln = 25;
constexpr int HWn = Hn * Wn;  // 8192

constexpr int TY = 4, TX = 16;   // 64 px per block
constexpr int HY = 8, HX = 24;   // halo rows x cols (y0-2..y0+5, x0-4..x0+19)
constexpr int RS = 136;          // hs row stride in halves (272 B)
constexpr int STS = 136;         // s_tile row stride in halves
constexpr int CC = 16;           // channels per transpose chunk
constexpr int BUFP = HY * HX + 1;  // 193 floats, bufA row stride (odd -> bank spread)

typedef __attribute__((ext_vector_type(8))) short short8;
typedef __attribute__((ext_vector_type(4))) float f32x4;

__device__ inline unsigned short f2bf(float f) {
    unsigned u = __float_as_uint(f);
    return (unsigned short)((u + 0x7fffu + ((u >> 16) & 1u)) >> 16);  // RNE
}

__global__ __launch_bounds__(256) void k_one(
    const float* __restrict__ attn, const float* __restrict__ fmap,
    const float* __restrict__ Wv, const float* __restrict__ gamma,
    float* __restrict__ out)
{
    __shared__ unsigned short hs[HY * HX * RS];            // 52.2 KB  [halo_px][c] bf16
    __shared__ float at_s[TY * TX * Ln];                   // 6.4 KB
    __shared__ __align__(16) char scratch[64 * STS * 2];   // 17.4 KB: bufA then s_tile
    unsigned short* s_tile = (unsigned short*)scratch;
    float* bufA = (float*)scratch;                          // 16*193*4 = 12.35 KB fits

    const int tid = threadIdx.x;
    const int b = blockIdx.z;
    const int x0 = blockIdx.x * TX;
    const int y0 = blockIdx.y * TY;
    const float g = gamma[0];

    // ---- stage attn (verbatim R5) ----
    for (int i = tid; i < TY * TX * Ln; i += 256) {
        int p = i / Ln, l = i - p * Ln;
        int n = (y0 + (p >> 4)) * Wn + x0 + (p & 15);
        at_s[i] = attn[((size_t)b * HWn + n) * Ln + l];
    }

    // ---- build hs: chunked in-LDS transpose of the f32 halo, f2bf on the way ----
    for (int kc = 0; kc < Cn; kc += CC) {
        __syncthreads();  // bufA free (prev chunk's transpose reads done); also fences at_s once
        for (int i = tid; i < CC * HY * HX; i += 256) {
            int c = i / (HY * HX), hp = i - c * (HY * HX);
            int hy = hp / HX, hx = hp - hy * HX;
            int ry = min(max(y0 + hy - 2, 0), Hn - 1);
            int gx = min(max(x0 + hx - 4, 0), Wn - 1);
            bufA[c * BUFP + hp] = fmap[((size_t)(b * Cn + kc + c) * Hn + ry) * Wn + gx];
        }
        __syncthreads();
        for (int i = tid; i < (CC / 2) * HY * HX; i += 256) {
            int cp = i & 7, hp = i >> 3;
            unsigned lo = f2bf(bufA[(2 * cp) * BUFP + hp]);
            unsigned hi = f2bf(bufA[(2 * cp + 1) * BUFP + hp]);
            *(unsigned*)&hs[hp * RS + kc + 2 * cp] = lo | (hi << 16);
        }
    }
    __syncthreads();

    // ---- stencil (verbatim R5; taps from hs) ----
    const int xi = tid & 15, kq = (tid >> 4) & 3, yi = tid >> 6;
    const int p = yi * 16 + xi;
    {
        float acc[32];
#pragma unroll
        for (int j = 0; j < 32; ++j) acc[j] = 0.f;
#pragma unroll
        for (int l = 0; l < Ln; ++l) {
            const int dy = l / 5, dx = l % 5;
            const float a = at_s[p * Ln + l];
            const unsigned short* row = &hs[((yi + dy) * HX + (2 + xi + dx)) * RS + kq * 32];
#pragma unroll
            for (int q = 0; q < 4; ++q) {
                uint4 u = *(const uint4*)&row[q * 8];
                const unsigned w[4] = {u.x, u.y, u.z, u.w};
#pragma unroll
                for (int e = 0; e < 4; ++e) {
                    acc[q * 8 + 2 * e + 0] += a * __uint_as_float(w[e] << 16);
                    acc[q * 8 + 2 * e + 1] += a * __uint_as_float(w[e] & 0xffff0000u);
                }
            }
        }
        unsigned short* dst = &s_tile[p * STS + kq * 32];
#pragma unroll
        for (int q = 0; q < 4; ++q) {
            unsigned pk[4];
#pragma unroll
            for (int e = 0; e < 4; ++e)
                pk[e] = (unsigned)f2bf(acc[q * 8 + 2 * e]) |
                        ((unsigned)f2bf(acc[q * 8 + 2 * e + 1]) << 16);
            uint4 v; v.x = pk[0]; v.y = pk[1]; v.z = pk[2]; v.w = pk[3];
            *(uint4*)&dst[q * 8] = v;
        }
    }
    __syncthreads();

    // ---- GEMM + epilogue (verbatim R5 structure; A-frags f2bf'd from Wv f32) ----
    const int wave = tid >> 6, lane = tid & 63;
    const int m16 = lane & 15, q = lane >> 4;

    short8 bfrag[4];
    const unsigned short* srow = &s_tile[(wave * 16 + m16) * STS + q * 8];
#pragma unroll
    for (int kk = 0; kk < 4; ++kk) bfrag[kk] = *(const short8*)(srow + kk * 32);

#pragma unroll
    for (int mg = 0; mg < 8; ++mg) {
        const float* arow = &Wv[(size_t)(mg * 16 + m16) * Cn + q * 8];
        f32x4 acc2 = {0.f, 0.f, 0.f, 0.f};
#pragma unroll
        for (int kk = 0; kk < 4; ++kk) {
            float4 w0 = *(const float4*)&arow[kk * 32];
            float4 w1 = *(const float4*)&arow[kk * 32 + 4];
            short8 af;
            af[0] = (short)f2bf(w0.x); af[1] = (short)f2bf(w0.y);
            af[2] = (short)f2bf(w0.z); af[3] = (short)f2bf(w0.w);
            af[4] = (short)f2bf(w1.x); af[5] = (short)f2bf(w1.y);
            af[6] = (short)f2bf(w1.z); af[7] = (short)f2bf(w1.w);
            acc2 = __builtin_amdgcn_mfma_f32_16x16x32_bf16(af, bfrag[kk], acc2, 0, 0, 0);
        }
        // D: col = lane&15 = px-in-row, row = q*4+r = channel-within-16
#pragma unroll
        for (int r = 0; r < 4; ++r) {
            const int c = mg * 16 + q * 4 + r;
            const size_t idx = ((size_t)(b * Cn + c)) * HWn + (y0 + wave) * Wn + x0 + m16;
            out[idx] = fmap[idx] + g * acc2[r];
        }
    }
}
}  // namespace

extern "C" void kernel_launch(void* const* d_in, const int* in_sizes, int n_in,
                              void* d_out, int out_size, void* d_ws, size_t ws_size,
                              hipStream_t stream) {
    const float* attn  = (const float*)d_in[0];
    const float* fmap  = (const float*)d_in[1];
    const float* Wv    = (const float*)d_in[2];
    const float* gamma = (const float*)d_in[3];
    float* out = (float*)d_out;
    (void)d_ws; (void)ws_size;  // no workspace needed

    dim3 g(Wn / TX, Hn / TY, Bn);  // 8 x 16 x 4 = 512 blocks
    k_one<<<g, 256, 0, stream>>>(attn, fmap, Wv, gamma, out);
}

// Round 9
// 146.824 us; speedup vs baseline: 1.1384x; 1.1384x over previous
//
#include <hip/hip_runtime.h>

// LSA v-first, barrier-minimal (R9). out = fmap + g*stencil_attn(u), u = Wv@fmap
// (exact by linearity). u kept PLANE-major so the stencil is all coalesced row
// loads -- no transpose, no big LDS, no per-phase barriers.
//   K_A: per 32-px tile: LDS transpose (R4-K_T pattern) -> bf16 [n][k] ->
//        MFMA GEMM (R4-K_V fragment paths) -> u[b][c][hw] bf16. 2 barriers.
//   K_B: attn staged to LDS once (1 barrier) -> 25-tap stencil via aligned
//        uint row loads + alignbit, fp32 accum, residual epilogue.
// B=4, C=128, H=64, W=128, L=25.

namespace {
constexpr int Bn = 4, Cn = 128, Hn = 64, Wn = 128, Ln = 25;
constexpr int HWn = Hn * Wn;  // 8192
constexpr int BTS = 134;      // K_A bf16 tile row stride (halves); 67 dwords, gcd(67,32)=1

typedef __attribute__((ext_vector_type(8))) short short8;
typedef __attribute__((ext_vector_type(4))) float f32x4;

__device__ inline unsigned short f2bf(float f) {
    unsigned u = __float_as_uint(f);
    return (unsigned short)((u + 0x7fffu + ((u >> 16) & 1u)) >> 16);  // RNE
}

// ---------------- K_A: u = Wv @ fmap, fused transpose + MFMA ----------------
__global__ __launch_bounds__(256) void k_ugemm(
    const float* __restrict__ fmap, const float* __restrict__ Wv,
    unsigned short* __restrict__ u)
{
    __shared__ float tile[Cn][33];              // 16.9 KB (R4-K_T verified layout)
    __shared__ unsigned short bT[32 * BTS];     // 8.6 KB  [n][k] bf16

    const int tid = threadIdx.x;
    const int b = blockIdx.y;
    const int n0 = blockIdx.x * 32;

    // stage fmap 128c x 32px (verbatim R4-K_T)
    for (int i = tid; i < Cn * 8; i += 256) {
        int c = i >> 3, q = i & 7;
        float4 v = *(const float4*)&fmap[((size_t)(b * Cn + c)) * HWn + n0 + q * 4];
        tile[c][q * 4 + 0] = v.x; tile[c][q * 4 + 1] = v.y;
        tile[c][q * 4 + 2] = v.z; tile[c][q * 4 + 3] = v.w;
    }
    __syncthreads();
    // repack transposed -> bT[n][k] bf16 (R4-K_T write pattern, dest = LDS)
    for (int i = tid; i < 32 * 64; i += 256) {
        int n = i & 31, cp = i >> 5;
        unsigned lo = f2bf(tile[2 * cp][n]), hi = f2bf(tile[2 * cp + 1][n]);
        *(unsigned*)&bT[n * BTS + 2 * cp] = lo | (hi << 16);
    }
    __syncthreads();

    // MFMA (R4-K_V fragment structure; A from Wv f32 + cvt, R8-verified path)
    const int wave = tid >> 6, lane = tid & 63;
    const int m16 = lane & 15, q = lane >> 4;
    const int ntile = wave >> 1;   // 0/1: px group
    const int mhalf = wave & 1;    // 0/1: channel half

    short8 bfrag[4];
    const unsigned short* srow = &bT[(ntile * 16 + m16) * BTS + q * 8];
#pragma unroll
    for (int kk = 0; kk < 4; ++kk) bfrag[kk] = *(const short8*)(srow + kk * 32);

#pragma unroll
    for (int mg = 0; mg < 4; ++mg) {
        const float* arow = &Wv[(size_t)(mhalf * 64 + mg * 16 + m16) * Cn + q * 8];
        f32x4 acc = {0.f, 0.f, 0.f, 0.f};
#pragma unroll
        for (int kk = 0; kk < 4; ++kk) {
            float4 w0 = *(const float4*)&arow[kk * 32];
            float4 w1 = *(const float4*)&arow[kk * 32 + 4];
            short8 af;
            af[0] = (short)f2bf(w0.x); af[1] = (short)f2bf(w0.y);
            af[2] = (short)f2bf(w0.z); af[3] = (short)f2bf(w0.w);
            af[4] = (short)f2bf(w1.x); af[5] = (short)f2bf(w1.y);
            af[6] = (short)f2bf(w1.z); af[7] = (short)f2bf(w1.w);
            acc = __builtin_amdgcn_mfma_f32_16x16x32_bf16(af, bfrag[kk], acc, 0, 0, 0);
        }
        // D: col = lane&15 = px, row = q*4+r = channel-within-16
#pragma unroll
        for (int r = 0; r < 4; ++r) {
            const int c = mhalf * 64 + mg * 16 + q * 4 + r;
            u[((size_t)(b * Cn + c)) * HWn + n0 + ntile * 16 + m16] = f2bf(acc[r]);
        }
    }
}

// ---------------- K_B: out = fmap + g * 25-tap stencil of u ----------------
// grid (chalf=2, y=64, b=4); thread: x2 = tid&63 (px pair), cs = tid>>6.
__global__ __launch_bounds__(256) void k_stencil(
    const unsigned short* __restrict__ u, const float* __restrict__ attn,
    const float* __restrict__ fmap, const float* __restrict__ gamma,
    float* __restrict__ out)
{
    __shared__ float at_s[Wn * Ln];  // 12.8 KB: attn rows for this y

    const int tid = threadIdx.x;
    const int ch = blockIdx.x;       // channel half
    const int y  = blockIdx.y;
    const int b  = blockIdx.z;
    const float g = gamma[0];

    // stage attn for the row (coalesced)
    const size_t abase = ((size_t)b * HWn + y * Wn) * Ln;
    for (int i = tid; i < Wn * Ln; i += 256) at_s[i] = attn[abase + i];
    __syncthreads();

    const int x2 = tid & 63, cs = tid >> 6;
    const int p0 = 2 * x2;           // even pixel; p1 = p0+1

    float a0[Ln], a1[Ln];
#pragma unroll
    for (int l = 0; l < Ln; ++l) {
        a0[l] = at_s[p0 * Ln + l];
        a1[l] = at_s[(p0 + 1) * Ln + l];
    }

    for (int it = 0; it < 16; ++it) {
        const int c = ch * 64 + it * 4 + cs;
        const size_t cbase = ((size_t)(b * Cn + c)) * HWn;
        float acc0 = 0.f, acc1 = 0.f;
#pragma unroll
        for (int dy = 0; dy < 5; ++dy) {
            const int ry = min(max(y + dy - 2, 0), Hn - 1);
            const unsigned short* ur = &u[cbase + ry * Wn];
            const unsigned Bv = *(const unsigned*)&ur[p0];
            unsigned Av, Cv;
            if (x2 == 0) { unsigned e = Bv & 0xffffu; Av = e | (e << 16); }
            else         { Av = *(const unsigned*)&ur[p0 - 2]; }
            if (x2 == 63) { unsigned e = Bv >> 16; Cv = e | (e << 16); }
            else          { Cv = *(const unsigned*)&ur[p0 + 2]; }
            const unsigned t[5] = {
                Av,
                (Bv << 16) | (Av >> 16),
                Bv,
                (Cv << 16) | (Bv >> 16),
                Cv };
#pragma unroll
            for (int dx = 0; dx < 5; ++dx) {
                const int l = dy * 5 + dx;
                acc0 += a0[l] * __uint_as_float(t[dx] << 16);
                acc1 += a1[l] * __uint_as_float(t[dx] & 0xffff0000u);
            }
        }
        const size_t idx = cbase + y * Wn + p0;
        float2 f = *(const float2*)&fmap[idx];
        float2 o;
        o.x = f.x + g * acc0;
        o.y = f.y + g * acc1;
        *(float2*)&out[idx] = o;
    }
}
}  // namespace

extern "C" void kernel_launch(void* const* d_in, const int* in_sizes, int n_in,
                              void* d_out, int out_size, void* d_ws, size_t ws_size,
                              hipStream_t stream) {
    const float* attn  = (const float*)d_in[0];
    const float* fmap  = (const float*)d_in[1];
    const float* Wv    = (const float*)d_in[2];
    const float* gamma = (const float*)d_in[3];
    float* out = (float*)d_out;

    unsigned short* u = (unsigned short*)d_ws;  // [B][C][HW] bf16, 8.39 MB

    dim3 gA(HWn / 32, Bn);   // 256 x 4 = 1024 blocks
    k_ugemm<<<gA, 256, 0, stream>>>(fmap, Wv, u);

    dim3 gB(2, Hn, Bn);      // 2 x 64 x 4 = 512 blocks
    k_stencil<<<gB, 256, 0, stream>>>(u, attn, fmap, gamma, out);
}